// Round 11
// baseline (142.449 us; speedup 1.0000x reference)
//
#include <hip/hip_runtime.h>
#include <math.h>

#define BATCH 16
#define CIN   256
#define NPIX  4096   // 64*64
#define NP4   1024   // 32*32 pooled
#define DQK   32     // C/8
#define DV    128    // C/2
#define KT    64     // keys per flash tile
#define QW    32     // queries per wave
#define QT    128    // queries per WG (4 waves)

typedef __attribute__((ext_vector_type(8)))  short short8v;
typedef __attribute__((ext_vector_type(16))) float f32x16;

#define ZERO16 {0.f,0.f,0.f,0.f,0.f,0.f,0.f,0.f,0.f,0.f,0.f,0.f,0.f,0.f,0.f,0.f}
#define LOG2E 1.44269504088896340736f
// Fixed softmax shift (log2 domain); see R10 notes. p = exp2(s-64).
#define MFIX 64.0f

__device__ __forceinline__ unsigned short f2bf(float f) {
    unsigned u = __float_as_uint(f);
    u += 0x7FFFu + ((u >> 16) & 1u);          // round-to-nearest-even
    return (unsigned short)(u >> 16);
}

__device__ __forceinline__ unsigned cvtpk(float a, float b) {
    unsigned r;
    asm("v_cvt_pk_bf16_f32 %0, %1, %2" : "=v"(r) : "v"(a), "v"(b));
    return r;
}

__device__ __forceinline__ short8v ldg8(const unsigned short* p) {
    return *(const short8v*)p;
}

#define PLSWAP(a, b) asm("v_permlane32_swap_b32 %0, %1" : "+v"(a), "+v"(b))

// -------- weight conversion: wqkv[192][256] = {theta,phi,g}, wab[256][128] --
__global__ void wcvt_k(const float* __restrict__ wt, const float* __restrict__ wp,
                       const float* __restrict__ wg, const float* __restrict__ wa,
                       unsigned short* __restrict__ wqkv, unsigned short* __restrict__ wab)
{
    int i = blockIdx.x * 256 + threadIdx.x;
    if (i < 192 * 256) {
        int row = i >> 8, c = i & 255;
        float v = row < 32 ? wt[row * 256 + c]
                : row < 64 ? wp[(row - 32) * 256 + c]
                           : wg[(row - 64) * 256 + c];
        wqkv[i] = f2bf(v);
    } else {
        int j = i - 192 * 256;
        if (j < 256 * DV) wab[j] = f2bf(wa[j]);
    }
}

// -------- fused QKV conv (MFMA) + 2x2 maxpool for K,V ----------------------
__global__ __launch_bounds__(256, 2) void conv_qkv_k(
    const float* __restrict__ x, const unsigned short* __restrict__ wqkv,
    const float* __restrict__ b_theta, const float* __restrict__ b_phi,
    const float* __restrict__ b_g, unsigned short* __restrict__ Qg,
    unsigned short* __restrict__ Kg, unsigned short* __restrict__ Vg)
{
    __shared__ __align__(16) union {
        unsigned short xs[2][2][128][8];   // [buf][k>>3][pixel][k&7]  8 KB
        float pool[2][160][32];            // [row-half][pooled ch][window] 40 KB
    } u;

    const int b    = blockIdx.y;
    const int tile = blockIdx.x;              // two image rows
    const int pixb = tile * 128;
    const int t    = threadIdx.x;
    const int wv   = t >> 6, l = t & 63, h = l >> 5, q31 = l & 31;
    const int sp   = t & 127, skb = t >> 7;   // staging: pixel, k-half

    const float* xb = x + (size_t)b * CIN * NPIX + pixb + sp;

    f32x16 acc[6];
#pragma unroll
    for (int i = 0; i < 6; ++i) acc[i] = ZERO16;

    float xa[8], xbr[8];
#pragma unroll
    for (int j = 0; j < 8; ++j) xa[j] = xb[(size_t)(skb * 8 + j) * NPIX];
    {
        unsigned pk[4];
#pragma unroll
        for (int jj = 0; jj < 4; ++jj) pk[jj] = cvtpk(xa[2*jj], xa[2*jj+1]);
        *(uint4*)&u.xs[0][skb][sp][0] = *(uint4*)pk;
    }
#pragma unroll
    for (int j = 0; j < 8; ++j) xbr[j] = xb[(size_t)(16 + skb * 8 + j) * NPIX];
    __syncthreads();

    for (int ks = 0; ks < 16; ks += 2) {
        if (ks < 14) {
            const float* xn = xb + (size_t)((ks + 2) * 16 + skb * 8) * NPIX;
#pragma unroll
            for (int j = 0; j < 8; ++j) xa[j] = xn[(size_t)j * NPIX];
        }
        {
            short8v bf = *(const short8v*)&u.xs[0][h][wv * 32 + q31][0];
#pragma unroll
            for (int rb = 0; rb < 6; ++rb) {
                short8v af = *(const short8v*)&wqkv[(size_t)(rb * 32 + q31) * 256 + ks * 16 + h * 8];
                acc[rb] = __builtin_amdgcn_mfma_f32_32x32x16_bf16(af, bf, acc[rb], 0, 0, 0);
            }
        }
        {
            unsigned pk[4];
#pragma unroll
            for (int jj = 0; jj < 4; ++jj) pk[jj] = cvtpk(xbr[2*jj], xbr[2*jj+1]);
            *(uint4*)&u.xs[1][skb][sp][0] = *(uint4*)pk;
        }
        __syncthreads();

        if (ks < 14) {
            const float* xn = xb + (size_t)((ks + 3) * 16 + skb * 8) * NPIX;
#pragma unroll
            for (int j = 0; j < 8; ++j) xbr[j] = xn[(size_t)j * NPIX];
        }
        {
            short8v bf = *(const short8v*)&u.xs[1][h][wv * 32 + q31][0];
#pragma unroll
            for (int rb = 0; rb < 6; ++rb) {
                short8v af = *(const short8v*)&wqkv[(size_t)(rb * 32 + q31) * 256 + (ks + 1) * 16 + h * 8];
                acc[rb] = __builtin_amdgcn_mfma_f32_32x32x16_bf16(af, bf, acc[rb], 0, 0, 0);
            }
        }
        if (ks < 14) {
            unsigned pk[4];
#pragma unroll
            for (int jj = 0; jj < 4; ++jj) pk[jj] = cvtpk(xa[2*jj], xa[2*jj+1]);
            *(uint4*)&u.xs[0][skb][sp][0] = *(uint4*)pk;
        }
        __syncthreads();
    }

    // ---- Q epilogue (rb 0): full-res, bf16 [p][32]; pre-scaled by log2(e)
    {
        int pix = pixb + wv * 32 + q31;
        unsigned short* qout = &Qg[((size_t)b * NPIX + pix) * DQK];
#pragma unroll
        for (int m = 0; m < 4; ++m) {
            unsigned pk2[2];
            float v0 = (acc[0][m*4+0] + b_theta[4*h + 8*m + 0]) * LOG2E;
            float v1 = (acc[0][m*4+1] + b_theta[4*h + 8*m + 1]) * LOG2E;
            float v2 = (acc[0][m*4+2] + b_theta[4*h + 8*m + 2]) * LOG2E;
            float v3 = (acc[0][m*4+3] + b_theta[4*h + 8*m + 3]) * LOG2E;
            pk2[0] = cvtpk(v0, v1);
            pk2[1] = cvtpk(v2, v3);
            *(uint2*)&qout[8*m + 4*h] = *(uint2*)pk2;
        }
    }

    // ---- pooled epilogue (rb 1..5): horizontal max via shfl, halves to LDS
#pragma unroll
    for (int rb = 1; rb < 6; ++rb) {
#pragma unroll
        for (int r = 0; r < 16; ++r) {
            float v  = acc[rb][r];
            float o  = __shfl_xor(v, 1);
            float mx = fmaxf(v, o);
            if ((q31 & 1) == 0) {
                int row = (r & 3) + 8 * (r >> 2) + 4 * h;
                u.pool[wv >> 1][(rb - 1) * 32 + row][(wv & 1) * 16 + (q31 >> 1)] = mx;
            }
        }
    }
    __syncthreads();

    // ---- vertical max + bias + scatter to K/V frag layouts
    {
        int wx = t & 31;
        int pp = tile * 32 + wx;
#pragma unroll
        for (int i = 0; i < 20; ++i) {
            int ch = (t >> 5) * 20 + i;
            float v = fmaxf(u.pool[0][ch][wx], u.pool[1][ch][wx]);
            if (ch < 32) {
                v += b_phi[ch];
                Kg[(((size_t)b * 4 + (ch >> 3)) * NP4 + pp) * 8 + (ch & 7)] = f2bf(v);
            } else {
                int c = ch - 32;
                v += b_g[c];
                Vg[((size_t)b * 128 + (pp >> 3)) * (DV * 8) + (size_t)c * 8 + (pp & 7)] = f2bf(v);
            }
        }
    }
}

// ------- flash attention (MFMA, no LDS staging, no barriers) -> Og ----------
// Writes only normalized O[b][p][c] bf16; final conv moved to conv_out_k.
__global__ __launch_bounds__(256, 2) void flash_k(
    const unsigned short* __restrict__ Qg, const unsigned short* __restrict__ Kg,
    const unsigned short* __restrict__ Vg, unsigned short* __restrict__ Og)
{
    // per-wave transpose buffer, q-dim padded 32->33 to break bank aliasing
    __shared__ __align__(16) unsigned short os[4][16 * 33 * 8];   // 33 KB

    const int b   = blockIdx.y;
    const int t   = threadIdx.x;
    const int wv  = t >> 6;
    const int l   = t & 63;
    const int h   = l >> 5;
    const int q31 = l & 31;
    const int p0  = blockIdx.x * QT + wv * QW;

    const unsigned short* Kp = Kg + (size_t)b * 4 * NP4 * 8 + ((size_t)h * NP4 + q31) * 8;
    const unsigned short* Vp = Vg + (size_t)b * 128 * DV * 8 + h * 1024 + q31 * 8;

    short8v qf0 = ldg8(&Qg[((size_t)b * NPIX + p0 + q31) * DQK + h * 8]);
    short8v qf1 = ldg8(&Qg[((size_t)b * NPIX + p0 + q31) * DQK + 16 + h * 8]);

    f32x16 o0 = ZERO16, o1 = ZERO16, o2 = ZERO16, o3 = ZERO16;
    float lsum = 0.f;

    short8v kfA[4], kfB[4], vg[16];
#pragma unroll
    for (int i = 0; i < 4; ++i)
        kfA[i] = ldg8(Kp + (i >> 1) * (2 * NP4 * 8) + (i & 1) * 256);
#pragma unroll
    for (int g = 0; g < 4; ++g)
#pragma unroll
        for (int cc = 0; cc < 4; ++cc)
            vg[g * 4 + cc] = ldg8(Vp + g * 2048 + cc * 256);

    auto tile = [&](int kt, short8v (&kfc)[4], short8v (&kfn)[4], bool pref) {
        f32x16 s0 = ZERO16, s1 = ZERO16;
        s0 = __builtin_amdgcn_mfma_f32_32x32x16_bf16(kfc[0], qf0, s0, 0, 0, 0);
        s1 = __builtin_amdgcn_mfma_f32_32x32x16_bf16(kfc[1], qf0, s1, 0, 0, 0);
        s0 = __builtin_amdgcn_mfma_f32_32x32x16_bf16(kfc[2], qf1, s0, 0, 0, 0);
        s1 = __builtin_amdgcn_mfma_f32_32x32x16_bf16(kfc[3], qf1, s1, 0, 0, 0);

        if (pref) {
            const unsigned short* kp1 = Kp + (size_t)(kt + 1) * 512;
#pragma unroll
            for (int i = 0; i < 4; ++i)
                kfn[i] = ldg8(kp1 + (i >> 1) * (2 * NP4 * 8) + (i & 1) * 256);
        }

        // fixed-shift softmax numerator + tree sum
        float ts[16];
#pragma unroll
        for (int r = 0; r < 16; ++r) {
            s0[r] = exp2f(s0[r] - MFIX);
            s1[r] = exp2f(s1[r] - MFIX);
            ts[r] = s0[r] + s1[r];
        }
#pragma unroll
        for (int d = 8; d >= 1; d >>= 1)
#pragma unroll
            for (int r = 0; r < d; ++r) ts[r] += ts[r + d];
        lsum += ts[0] + __shfl_xor(ts[0], 32);

        // P -> bf16 PV A-frags: cvt_pk + permlane32_swap
        unsigned ca[8], cb[8];
#pragma unroll
        for (int j = 0; j < 8; ++j) {
            ca[j] = cvtpk(s0[2*j], s0[2*j+1]);
            cb[j] = cvtpk(s1[2*j], s1[2*j+1]);
        }
        PLSWAP(ca[0], ca[2]); PLSWAP(ca[1], ca[3]);
        PLSWAP(ca[4], ca[6]); PLSWAP(ca[5], ca[7]);
        PLSWAP(cb[0], cb[2]); PLSWAP(cb[1], cb[3]);
        PLSWAP(cb[4], cb[6]); PLSWAP(cb[5], cb[7]);
        union { unsigned uu[4]; short8v v; } pa[4];
#pragma unroll
        for (int j = 0; j < 4; ++j) {
            pa[0].uu[j] = ca[j];     pa[1].uu[j] = ca[4 + j];
            pa[2].uu[j] = cb[j];     pa[3].uu[j] = cb[4 + j];
        }

        const unsigned short* vp1 = Vp + (size_t)(kt + 1) * 8192;
#pragma unroll
        for (int g = 0; g < 4; ++g) {
            o0 = __builtin_amdgcn_mfma_f32_32x32x16_bf16(pa[g].v, vg[g*4+0], o0, 0, 0, 0);
            o1 = __builtin_amdgcn_mfma_f32_32x32x16_bf16(pa[g].v, vg[g*4+1], o1, 0, 0, 0);
            o2 = __builtin_amdgcn_mfma_f32_32x32x16_bf16(pa[g].v, vg[g*4+2], o2, 0, 0, 0);
            o3 = __builtin_amdgcn_mfma_f32_32x32x16_bf16(pa[g].v, vg[g*4+3], o3, 0, 0, 0);
            if (pref) {
#pragma unroll
                for (int cc = 0; cc < 4; ++cc)
                    vg[g*4+cc] = ldg8(vp1 + g * 2048 + cc * 256);
            }
        }
    };

    for (int kt = 0; kt < 16; kt += 2) {
        tile(kt,     kfA, kfB, true);
        tile(kt + 1, kfB, kfA, kt + 1 < 15);
    }

    // ---- normalize; per-wave padded-LDS transpose; coalesced Og write (1KB/instr)
    float rinv = 1.0f / lsum;
    unsigned short* osw = os[wv];
#pragma unroll
    for (int r = 0; r < 16; ++r) {
        int q = (r & 3) + 8 * (r >> 2) + 4 * h;
        float rn = __shfl(rinv, q);
        int e = l & 7;
        osw[(((q31 >> 3)     ) * 33 + q) * 8 + e] = f2bf(o0[r] * rn);
        osw[(((q31 >> 3) +  4) * 33 + q) * 8 + e] = f2bf(o1[r] * rn);
        osw[(((q31 >> 3) +  8) * 33 + q) * 8 + e] = f2bf(o2[r] * rn);
        osw[(((q31 >> 3) + 12) * 33 + q) * 8 + e] = f2bf(o3[r] * rn);
    }
    {
        unsigned short* og = Og + ((size_t)b * NPIX + p0) * DV;
        int cb = l & 15, qof = l >> 4;
#pragma unroll
        for (int j = 0; j < 8; ++j) {
            int q = j * 4 + qof;
            short8v v = *(const short8v*)&osw[(cb * 33 + q) * 8];
            *(short8v*)&og[(size_t)q * DV + cb * 8] = v;
        }
    }
}

// ------- streaming final conv: out = x + sigma*(W*O^T + bias) ---------------
// Grid (32 px-tiles, 2 ch-halves, 16 b) = 1024 blocks, 4 waves. Tile 128ch x 128px.
__global__ __launch_bounds__(256, 2) void conv_out_k(
    const unsigned short* __restrict__ Og, const unsigned short* __restrict__ wab,
    const float* __restrict__ b_attn, const float* __restrict__ sigma,
    const float* __restrict__ x, float* __restrict__ out)
{
    __shared__ __align__(16) float ls[32][132];     // 16.9 KB bounce buffer

    const int b   = blockIdx.z;
    const int chH = blockIdx.y;                     // ch half (128)
    const int px0 = blockIdx.x * 128;
    const int t   = threadIdx.x;
    const int wv  = t >> 6;
    const int l   = t & 63;
    const int h   = l >> 5;
    const int q31 = l & 31;
    const int pxw = px0 + wv * 32;                  // wave's px base

    // B-frags: O^T columns = px; of[k16] from Og[b][px][k16*16+h*8]
    const unsigned short* ob = Og + ((size_t)b * NPIX + pxw + q31) * DV;
    short8v of[8];
#pragma unroll
    for (int k = 0; k < 8; ++k) of[k] = ldg8(ob + k * 16 + h * 8);

    // 32 MFMAs: e[chb] = W[ch-tile] x O^T
    f32x16 e[4];
#pragma unroll
    for (int i = 0; i < 4; ++i) e[i] = ZERO16;
    const unsigned short* wb = wab + (size_t)(chH * 128) * DV;
#pragma unroll
    for (int chb = 0; chb < 4; ++chb)
#pragma unroll
        for (int k = 0; k < 8; ++k) {
            short8v wf = ldg8(wb + (size_t)(chb * 32 + q31) * DV + k * 16 + h * 8);
            e[chb] = __builtin_amdgcn_mfma_f32_32x32x16_bf16(wf, of[k], e[chb], 0, 0, 0);
        }

    const float sg = sigma[0];
    // per 32-ch group: LDS bounce -> float4 streaming IO (512B segments)
#pragma unroll 1
    for (int chb = 0; chb < 4; ++chb) {
#pragma unroll
        for (int r = 0; r < 16; ++r) {
            int crow = (r & 3) + 8 * (r >> 2) + 4 * h;
            ls[crow][wv * 32 + q31] = e[chb][r];
        }
        __syncthreads();
        // 4 passes x (8 ch x 32 float4) : lanes 0-31 same channel -> 512B runs
#pragma unroll
        for (int rep = 0; rep < 4; ++rep) {
            int cl  = rep * 8 + (t >> 5);           // 0..31 local ch
            int ch  = chH * 128 + chb * 32 + cl;
            int px4 = (t & 31) * 4;
            float4 v = *(const float4*)&ls[cl][px4];
            float bias = b_attn[ch];
            size_t idx = ((size_t)b * 256 + ch) * NPIX + px0 + px4;
            float4 xv = *(const float4*)&x[idx];
            float4 o;
            o.x = fmaf(sg, v.x + bias, xv.x);
            o.y = fmaf(sg, v.y + bias, xv.y);
            o.z = fmaf(sg, v.z + bias, xv.z);
            o.w = fmaf(sg, v.w + bias, xv.w);
            *(float4*)&out[idx] = o;
        }
        __syncthreads();
    }
}

extern "C" void kernel_launch(void* const* d_in, const int* in_sizes, int n_in,
                              void* d_out, int out_size, void* d_ws, size_t ws_size,
                              hipStream_t stream) {
    const float* x       = (const float*)d_in[0];
    const float* w_theta = (const float*)d_in[1];
    const float* b_theta = (const float*)d_in[2];
    const float* w_phi   = (const float*)d_in[3];
    const float* b_phi   = (const float*)d_in[4];
    const float* w_g     = (const float*)d_in[5];
    const float* b_g     = (const float*)d_in[6];
    const float* w_attn  = (const float*)d_in[7];
    const float* b_attn  = (const float*)d_in[8];
    const float* sigma   = (const float*)d_in[9];
    float* out = (float*)d_out;

    unsigned short* Qg   = (unsigned short*)d_ws;                 // 16*4096*32
    unsigned short* Kg   = Qg + (size_t)BATCH * NPIX * DQK;       // 16*4*1024*8
    unsigned short* Vg   = Kg + (size_t)BATCH * 4 * NP4 * 8;      // 16*128*128*8
    unsigned short* wab  = Vg + (size_t)BATCH * 128 * DV * 8;     // 256*128
    unsigned short* wqkv = wab + (size_t)256 * DV;                // 192*256
    unsigned short* Og   = wqkv + (size_t)192 * 256;              // 16*4096*128

    wcvt_k    <<<dim3((192 * 256 + 256 * DV + 255) / 256), 256, 0, stream>>>(
        w_theta, w_phi, w_g, w_attn, wqkv, wab);
    conv_qkv_k<<<dim3(NPIX / 128, BATCH), 256, 0, stream>>>(
        x, wqkv, b_theta, b_phi, b_g, Qg, Kg, Vg);
    flash_k   <<<dim3(NPIX / QT, BATCH), 256, 0, stream>>>(Qg, Kg, Vg, Og);
    conv_out_k<<<dim3(NPIX / 128, 2, BATCH), 256, 0, stream>>>(
        Og, wab, b_attn, sigma, x, out);
}

// Round 12
// 104.358 us; speedup vs baseline: 1.3650x; 1.3650x over previous
//
#include <hip/hip_runtime.h>
#include <math.h>

#define BATCH 16
#define CIN   256
#define NPIX  4096   // 64*64
#define NP4   1024   // 32*32 pooled
#define DQK   32     // C/8
#define DV    128    // C/2
#define QW    32     // queries per wave
#define QT    128    // queries per WG (4 waves)

typedef __attribute__((ext_vector_type(8)))  short short8v;
typedef __attribute__((ext_vector_type(16))) float f32x16;

#define ZERO16 {0.f,0.f,0.f,0.f,0.f,0.f,0.f,0.f,0.f,0.f,0.f,0.f,0.f,0.f,0.f,0.f}
#define LOG2E 1.44269504088896340736f
// Fixed softmax shift (log2 domain); see R10 notes. p = exp2(s-64).
#define MFIX 64.0f

__device__ __forceinline__ unsigned short f2bf(float f) {
    unsigned u = __float_as_uint(f);
    u += 0x7FFFu + ((u >> 16) & 1u);          // round-to-nearest-even
    return (unsigned short)(u >> 16);
}

__device__ __forceinline__ unsigned cvtpk(float a, float b) {
    unsigned r;
    asm("v_cvt_pk_bf16_f32 %0, %1, %2" : "=v"(r) : "v"(a), "v"(b));
    return r;
}

__device__ __forceinline__ short8v ldg8(const unsigned short* p) {
    return *(const short8v*)p;
}

#define PLSWAP(a, b) asm("v_permlane32_swap_b32 %0, %1" : "+v"(a), "+v"(b))

// -------- weight conversion: wqkv[192][256] = {theta,phi,g}, wab[256][128] --
__global__ void wcvt_k(const float* __restrict__ wt, const float* __restrict__ wp,
                       const float* __restrict__ wg, const float* __restrict__ wa,
                       unsigned short* __restrict__ wqkv, unsigned short* __restrict__ wab)
{
    int i = blockIdx.x * 256 + threadIdx.x;
    if (i < 192 * 256) {
        int row = i >> 8, c = i & 255;
        float v = row < 32 ? wt[row * 256 + c]
                : row < 64 ? wp[(row - 32) * 256 + c]
                           : wg[(row - 64) * 256 + c];
        wqkv[i] = f2bf(v);
    } else {
        int j = i - 192 * 256;
        if (j < 256 * DV) wab[j] = f2bf(wa[j]);
    }
}

// -------- fused QKV conv (MFMA) + 2x2 maxpool for K,V ----------------------
__global__ __launch_bounds__(256, 2) void conv_qkv_k(
    const float* __restrict__ x, const unsigned short* __restrict__ wqkv,
    const float* __restrict__ b_theta, const float* __restrict__ b_phi,
    const float* __restrict__ b_g, unsigned short* __restrict__ Qg,
    unsigned short* __restrict__ Kg, unsigned short* __restrict__ Vg)
{
    __shared__ __align__(16) union {
        unsigned short xs[2][2][128][8];   // [buf][k>>3][pixel][k&7]  8 KB
        float pool[2][160][32];            // [row-half][pooled ch][window] 40 KB
    } u;

    const int b    = blockIdx.y;
    const int tile = blockIdx.x;              // two image rows
    const int pixb = tile * 128;
    const int t    = threadIdx.x;
    const int wv   = t >> 6, l = t & 63, h = l >> 5, q31 = l & 31;
    const int sp   = t & 127, skb = t >> 7;   // staging: pixel, k-half

    const float* xb = x + (size_t)b * CIN * NPIX + pixb + sp;

    f32x16 acc[6];
#pragma unroll
    for (int i = 0; i < 6; ++i) acc[i] = ZERO16;

    float xa[8], xbr[8];
#pragma unroll
    for (int j = 0; j < 8; ++j) xa[j] = xb[(size_t)(skb * 8 + j) * NPIX];
    {
        unsigned pk[4];
#pragma unroll
        for (int jj = 0; jj < 4; ++jj) pk[jj] = cvtpk(xa[2*jj], xa[2*jj+1]);
        *(uint4*)&u.xs[0][skb][sp][0] = *(uint4*)pk;
    }
#pragma unroll
    for (int j = 0; j < 8; ++j) xbr[j] = xb[(size_t)(16 + skb * 8 + j) * NPIX];
    __syncthreads();

    for (int ks = 0; ks < 16; ks += 2) {
        if (ks < 14) {
            const float* xn = xb + (size_t)((ks + 2) * 16 + skb * 8) * NPIX;
#pragma unroll
            for (int j = 0; j < 8; ++j) xa[j] = xn[(size_t)j * NPIX];
        }
        {
            short8v bf = *(const short8v*)&u.xs[0][h][wv * 32 + q31][0];
#pragma unroll
            for (int rb = 0; rb < 6; ++rb) {
                short8v af = *(const short8v*)&wqkv[(size_t)(rb * 32 + q31) * 256 + ks * 16 + h * 8];
                acc[rb] = __builtin_amdgcn_mfma_f32_32x32x16_bf16(af, bf, acc[rb], 0, 0, 0);
            }
        }
        {
            unsigned pk[4];
#pragma unroll
            for (int jj = 0; jj < 4; ++jj) pk[jj] = cvtpk(xbr[2*jj], xbr[2*jj+1]);
            *(uint4*)&u.xs[1][skb][sp][0] = *(uint4*)pk;
        }
        __syncthreads();

        if (ks < 14) {
            const float* xn = xb + (size_t)((ks + 3) * 16 + skb * 8) * NPIX;
#pragma unroll
            for (int j = 0; j < 8; ++j) xbr[j] = xn[(size_t)j * NPIX];
        }
        {
            short8v bf = *(const short8v*)&u.xs[1][h][wv * 32 + q31][0];
#pragma unroll
            for (int rb = 0; rb < 6; ++rb) {
                short8v af = *(const short8v*)&wqkv[(size_t)(rb * 32 + q31) * 256 + (ks + 1) * 16 + h * 8];
                acc[rb] = __builtin_amdgcn_mfma_f32_32x32x16_bf16(af, bf, acc[rb], 0, 0, 0);
            }
        }
        if (ks < 14) {
            unsigned pk[4];
#pragma unroll
            for (int jj = 0; jj < 4; ++jj) pk[jj] = cvtpk(xa[2*jj], xa[2*jj+1]);
            *(uint4*)&u.xs[0][skb][sp][0] = *(uint4*)pk;
        }
        __syncthreads();
    }

    // ---- Q epilogue (rb 0): full-res, bf16 [p][32]; pre-scaled by log2(e)
    {
        int pix = pixb + wv * 32 + q31;
        unsigned short* qout = &Qg[((size_t)b * NPIX + pix) * DQK];
#pragma unroll
        for (int m = 0; m < 4; ++m) {
            unsigned pk2[2];
            float v0 = (acc[0][m*4+0] + b_theta[4*h + 8*m + 0]) * LOG2E;
            float v1 = (acc[0][m*4+1] + b_theta[4*h + 8*m + 1]) * LOG2E;
            float v2 = (acc[0][m*4+2] + b_theta[4*h + 8*m + 2]) * LOG2E;
            float v3 = (acc[0][m*4+3] + b_theta[4*h + 8*m + 3]) * LOG2E;
            pk2[0] = cvtpk(v0, v1);
            pk2[1] = cvtpk(v2, v3);
            *(uint2*)&qout[8*m + 4*h] = *(uint2*)pk2;
        }
    }

    // ---- pooled epilogue (rb 1..5): horizontal max via shfl, halves to LDS
#pragma unroll
    for (int rb = 1; rb < 6; ++rb) {
#pragma unroll
        for (int r = 0; r < 16; ++r) {
            float v  = acc[rb][r];
            float o  = __shfl_xor(v, 1);
            float mx = fmaxf(v, o);
            if ((q31 & 1) == 0) {
                int row = (r & 3) + 8 * (r >> 2) + 4 * h;
                u.pool[wv >> 1][(rb - 1) * 32 + row][(wv & 1) * 16 + (q31 >> 1)] = mx;
            }
        }
    }
    __syncthreads();

    // ---- vertical max + bias + scatter to K/V frag layouts
    {
        int wx = t & 31;
        int pp = tile * 32 + wx;
#pragma unroll
        for (int i = 0; i < 20; ++i) {
            int ch = (t >> 5) * 20 + i;
            float v = fmaxf(u.pool[0][ch][wx], u.pool[1][ch][wx]);
            if (ch < 32) {
                v += b_phi[ch];
                Kg[(((size_t)b * 4 + (ch >> 3)) * NP4 + pp) * 8 + (ch & 7)] = f2bf(v);
            } else {
                int c = ch - 32;
                v += b_g[c];
                Vg[((size_t)b * 128 + (pp >> 3)) * (DV * 8) + (size_t)c * 8 + (pp & 7)] = f2bf(v);
            }
        }
    }
}

// ------- fused: flash attention + final conv + residual ---------------------
// Main loop: reg-resident K/V direct from global, no barriers, fixed-shift SM.
// Epilogue: per-wave O transpose (osw) -> per-cht block LDS bounce (ls) ->
// float4 IO with 512B contiguous segments; x loads hoisted above MFMAs.
__global__ __launch_bounds__(256, 2) void flash_k(
    const unsigned short* __restrict__ Qg, const unsigned short* __restrict__ Kg,
    const unsigned short* __restrict__ Vg, const unsigned short* __restrict__ wab,
    const float* __restrict__ b_attn, const float* __restrict__ sigma,
    const float* __restrict__ x, float* __restrict__ out)
{
    __shared__ __align__(16) unsigned short os[4][16 * 33 * 8];  // 33.8 KB per-wave O^T
    __shared__ __align__(16) float ls[32][132];                  // 16.9 KB cht bounce

    const int b    = blockIdx.y;
    const int t    = threadIdx.x;
    const int wv   = t >> 6;
    const int l    = t & 63;
    const int h    = l >> 5;
    const int q31  = l & 31;
    const int pxblk = blockIdx.x * QT;
    const int p0   = pxblk + wv * QW;

    const unsigned short* Kp = Kg + (size_t)b * 4 * NP4 * 8 + ((size_t)h * NP4 + q31) * 8;
    const unsigned short* Vp = Vg + (size_t)b * 128 * DV * 8 + h * 1024 + q31 * 8;

    short8v qf0 = ldg8(&Qg[((size_t)b * NPIX + p0 + q31) * DQK + h * 8]);
    short8v qf1 = ldg8(&Qg[((size_t)b * NPIX + p0 + q31) * DQK + 16 + h * 8]);

    f32x16 o0 = ZERO16, o1 = ZERO16, o2 = ZERO16, o3 = ZERO16;
    float lsum = 0.f;

    short8v kfA[4], kfB[4], vg[16];
#pragma unroll
    for (int i = 0; i < 4; ++i)
        kfA[i] = ldg8(Kp + (i >> 1) * (2 * NP4 * 8) + (i & 1) * 256);
#pragma unroll
    for (int g = 0; g < 4; ++g)
#pragma unroll
        for (int cc = 0; cc < 4; ++cc)
            vg[g * 4 + cc] = ldg8(Vp + g * 2048 + cc * 256);

    auto tile = [&](int kt, short8v (&kfc)[4], short8v (&kfn)[4], bool pref) {
        f32x16 s0 = ZERO16, s1 = ZERO16;
        s0 = __builtin_amdgcn_mfma_f32_32x32x16_bf16(kfc[0], qf0, s0, 0, 0, 0);
        s1 = __builtin_amdgcn_mfma_f32_32x32x16_bf16(kfc[1], qf0, s1, 0, 0, 0);
        s0 = __builtin_amdgcn_mfma_f32_32x32x16_bf16(kfc[2], qf1, s0, 0, 0, 0);
        s1 = __builtin_amdgcn_mfma_f32_32x32x16_bf16(kfc[3], qf1, s1, 0, 0, 0);

        if (pref) {
            const unsigned short* kp1 = Kp + (size_t)(kt + 1) * 512;
#pragma unroll
            for (int i = 0; i < 4; ++i)
                kfn[i] = ldg8(kp1 + (i >> 1) * (2 * NP4 * 8) + (i & 1) * 256);
        }

        float ts[16];
#pragma unroll
        for (int r = 0; r < 16; ++r) {
            s0[r] = exp2f(s0[r] - MFIX);
            s1[r] = exp2f(s1[r] - MFIX);
            ts[r] = s0[r] + s1[r];
        }
#pragma unroll
        for (int d = 8; d >= 1; d >>= 1)
#pragma unroll
            for (int r = 0; r < d; ++r) ts[r] += ts[r + d];
        lsum += ts[0] + __shfl_xor(ts[0], 32);

        unsigned ca[8], cb[8];
#pragma unroll
        for (int j = 0; j < 8; ++j) {
            ca[j] = cvtpk(s0[2*j], s0[2*j+1]);
            cb[j] = cvtpk(s1[2*j], s1[2*j+1]);
        }
        PLSWAP(ca[0], ca[2]); PLSWAP(ca[1], ca[3]);
        PLSWAP(ca[4], ca[6]); PLSWAP(ca[5], ca[7]);
        PLSWAP(cb[0], cb[2]); PLSWAP(cb[1], cb[3]);
        PLSWAP(cb[4], cb[6]); PLSWAP(cb[5], cb[7]);
        union { unsigned uu[4]; short8v v; } pa[4];
#pragma unroll
        for (int j = 0; j < 4; ++j) {
            pa[0].uu[j] = ca[j];     pa[1].uu[j] = ca[4 + j];
            pa[2].uu[j] = cb[j];     pa[3].uu[j] = cb[4 + j];
        }

        const unsigned short* vp1 = Vp + (size_t)(kt + 1) * 8192;
#pragma unroll
        for (int g = 0; g < 4; ++g) {
            o0 = __builtin_amdgcn_mfma_f32_32x32x16_bf16(pa[g].v, vg[g*4+0], o0, 0, 0, 0);
            o1 = __builtin_amdgcn_mfma_f32_32x32x16_bf16(pa[g].v, vg[g*4+1], o1, 0, 0, 0);
            o2 = __builtin_amdgcn_mfma_f32_32x32x16_bf16(pa[g].v, vg[g*4+2], o2, 0, 0, 0);
            o3 = __builtin_amdgcn_mfma_f32_32x32x16_bf16(pa[g].v, vg[g*4+3], o3, 0, 0, 0);
            if (pref) {
#pragma unroll
                for (int cc = 0; cc < 4; ++cc)
                    vg[g*4+cc] = ldg8(vp1 + g * 2048 + cc * 256);
            }
        }
    };

    for (int kt = 0; kt < 16; kt += 2) {
        tile(kt,     kfA, kfB, true);
        tile(kt + 1, kfB, kfA, kt + 1 < 15);
    }

    // ---- normalize + per-wave padded transpose (O^T as B-frag source)
    float rinv = 1.0f / lsum;
    unsigned short* osw = os[wv];
#pragma unroll
    for (int r = 0; r < 16; ++r) {
        int q = (r & 3) + 8 * (r >> 2) + 4 * h;
        float rn = __shfl(rinv, q);
        int e8 = l & 7;
        osw[(((q31 >> 3)     ) * 33 + q) * 8 + e8] = f2bf(o0[r] * rn);
        osw[(((q31 >> 3) +  4) * 33 + q) * 8 + e8] = f2bf(o1[r] * rn);
        osw[(((q31 >> 3) +  8) * 33 + q) * 8 + e8] = f2bf(o2[r] * rn);
        osw[(((q31 >> 3) + 12) * 33 + q) * 8 + e8] = f2bf(o3[r] * rn);
    }

    // ---- final conv + residual, wide-IO via block ls bounce
    const float sg = sigma[0];
    const int cl8  = t >> 5;                   // 0..7
    const int px4  = (t & 31) * 4;             // 0..124
#pragma unroll 1
    for (int cht = 0; cht < 8; ++cht) {
        // hoist residual x loads (independent of MFMAs below)
        float4 xv[4];
#pragma unroll
        for (int rep = 0; rep < 4; ++rep) {
            int ch = cht * 32 + rep * 8 + cl8;
            xv[rep] = *(const float4*)&x[((size_t)b * 256 + ch) * NPIX + pxblk + px4];
        }

        f32x16 e = ZERO16;
#pragma unroll
        for (int ks16 = 0; ks16 < 8; ++ks16) {
            short8v wf = ldg8(&wab[(size_t)(cht * 32 + q31) * DV + ks16 * 16 + h * 8]);
            short8v of = *(const short8v*)&osw[((ks16 * 2 + h) * 33 + q31) * 8];
            e = __builtin_amdgcn_mfma_f32_32x32x16_bf16(wf, of, e, 0, 0, 0);
        }
#pragma unroll
        for (int r = 0; r < 16; ++r) {
            int crow = (r & 3) + 8 * (r >> 2) + 4 * h;
            ls[crow][wv * 32 + q31] = e[r];
        }
        __syncthreads();
#pragma unroll
        for (int rep = 0; rep < 4; ++rep) {
            int cl = rep * 8 + cl8;
            int ch = cht * 32 + cl;
            float4 v = *(const float4*)&ls[cl][px4];
            float bias = b_attn[ch];
            size_t idx = ((size_t)b * 256 + ch) * NPIX + pxblk + px4;
            float4 o;
            o.x = fmaf(sg, v.x + bias, xv[rep].x);
            o.y = fmaf(sg, v.y + bias, xv[rep].y);
            o.z = fmaf(sg, v.z + bias, xv[rep].z);
            o.w = fmaf(sg, v.w + bias, xv[rep].w);
            *(float4*)&out[idx] = o;
        }
        __syncthreads();
    }
}

extern "C" void kernel_launch(void* const* d_in, const int* in_sizes, int n_in,
                              void* d_out, int out_size, void* d_ws, size_t ws_size,
                              hipStream_t stream) {
    const float* x       = (const float*)d_in[0];
    const float* w_theta = (const float*)d_in[1];
    const float* b_theta = (const float*)d_in[2];
    const float* w_phi   = (const float*)d_in[3];
    const float* b_phi   = (const float*)d_in[4];
    const float* w_g     = (const float*)d_in[5];
    const float* b_g     = (const float*)d_in[6];
    const float* w_attn  = (const float*)d_in[7];
    const float* b_attn  = (const float*)d_in[8];
    const float* sigma   = (const float*)d_in[9];
    float* out = (float*)d_out;

    unsigned short* Qg   = (unsigned short*)d_ws;                 // 16*4096*32
    unsigned short* Kg   = Qg + (size_t)BATCH * NPIX * DQK;       // 16*4*1024*8
    unsigned short* Vg   = Kg + (size_t)BATCH * 4 * NP4 * 8;      // 16*128*128*8
    unsigned short* wab  = Vg + (size_t)BATCH * 128 * DV * 8;     // 256*128
    unsigned short* wqkv = wab + (size_t)256 * DV;                // 192*256

    wcvt_k    <<<dim3((192 * 256 + 256 * DV + 255) / 256), 256, 0, stream>>>(
        w_theta, w_phi, w_g, w_attn, wqkv, wab);
    conv_qkv_k<<<dim3(NPIX / 128, BATCH), 256, 0, stream>>>(
        x, wqkv, b_theta, b_phi, b_g, Qg, Kg, Vg);
    flash_k   <<<dim3(NPIX / QT, BATCH), 256, 0, stream>>>(
        Qg, Kg, Vg, wab, b_attn, sigma, x, out);
}

// Round 13
// 102.687 us; speedup vs baseline: 1.3872x; 1.0163x over previous
//
#include <hip/hip_runtime.h>
#include <math.h>

#define BATCH 16
#define CIN   256
#define NPIX  4096   // 64*64
#define NP4   1024   // 32*32 pooled
#define DQK   32     // C/8
#define DV    128    // C/2
#define QW    32     // queries per wave
#define QT    128    // queries per WG (4 waves)

typedef __attribute__((ext_vector_type(8)))  short short8v;
typedef __attribute__((ext_vector_type(16))) float f32x16;

#define ZERO16 {0.f,0.f,0.f,0.f,0.f,0.f,0.f,0.f,0.f,0.f,0.f,0.f,0.f,0.f,0.f,0.f}
#define LOG2E 1.44269504088896340736f
// Fixed softmax shift (log2 domain); see R10 notes. p = exp2(s-64).
#define MFIX 64.0f

__device__ __forceinline__ unsigned short f2bf(float f) {
    unsigned u = __float_as_uint(f);
    u += 0x7FFFu + ((u >> 16) & 1u);          // round-to-nearest-even
    return (unsigned short)(u >> 16);
}

__device__ __forceinline__ unsigned cvtpk(float a, float b) {
    unsigned r;
    asm("v_cvt_pk_bf16_f32 %0, %1, %2" : "=v"(r) : "v"(a), "v"(b));
    return r;
}

__device__ __forceinline__ short8v ldg8(const unsigned short* p) {
    return *(const short8v*)p;
}

#define PLSWAP(a, b) asm("v_permlane32_swap_b32 %0, %1" : "+v"(a), "+v"(b))

// -------- weight conversion: wqkv[192][256] = {theta,phi,g}, wab[256][128] --
__global__ void wcvt_k(const float* __restrict__ wt, const float* __restrict__ wp,
                       const float* __restrict__ wg, const float* __restrict__ wa,
                       unsigned short* __restrict__ wqkv, unsigned short* __restrict__ wab)
{
    int i = blockIdx.x * 256 + threadIdx.x;
    if (i < 192 * 256) {
        int row = i >> 8, c = i & 255;
        float v = row < 32 ? wt[row * 256 + c]
                : row < 64 ? wp[(row - 32) * 256 + c]
                           : wg[(row - 64) * 256 + c];
        wqkv[i] = f2bf(v);
    } else {
        int j = i - 192 * 256;
        if (j < 256 * DV) wab[j] = f2bf(wa[j]);
    }
}

// -------- fused QKV conv (MFMA) + 2x2 maxpool for K,V ----------------------
__global__ __launch_bounds__(256, 2) void conv_qkv_k(
    const float* __restrict__ x, const unsigned short* __restrict__ wqkv,
    const float* __restrict__ b_theta, const float* __restrict__ b_phi,
    const float* __restrict__ b_g, unsigned short* __restrict__ Qg,
    unsigned short* __restrict__ Kg, unsigned short* __restrict__ Vg)
{
    __shared__ __align__(16) union {
        unsigned short xs[2][2][128][8];   // [buf][k>>3][pixel][k&7]  8 KB
        float pool[2][160][32];            // [row-half][pooled ch][window] 40 KB
    } u;

    const int b    = blockIdx.y;
    const int tile = blockIdx.x;              // two image rows
    const int pixb = tile * 128;
    const int t    = threadIdx.x;
    const int wv   = t >> 6, l = t & 63, h = l >> 5, q31 = l & 31;
    const int sp   = t & 127, skb = t >> 7;   // staging: pixel, k-half

    const float* xb = x + (size_t)b * CIN * NPIX + pixb + sp;

    f32x16 acc[6];
#pragma unroll
    for (int i = 0; i < 6; ++i) acc[i] = ZERO16;

    float xa[8], xbr[8];
#pragma unroll
    for (int j = 0; j < 8; ++j) xa[j] = xb[(size_t)(skb * 8 + j) * NPIX];
    {
        unsigned pk[4];
#pragma unroll
        for (int jj = 0; jj < 4; ++jj) pk[jj] = cvtpk(xa[2*jj], xa[2*jj+1]);
        *(uint4*)&u.xs[0][skb][sp][0] = *(uint4*)pk;
    }
#pragma unroll
    for (int j = 0; j < 8; ++j) xbr[j] = xb[(size_t)(16 + skb * 8 + j) * NPIX];
    __syncthreads();

    for (int ks = 0; ks < 16; ks += 2) {
        if (ks < 14) {
            const float* xn = xb + (size_t)((ks + 2) * 16 + skb * 8) * NPIX;
#pragma unroll
            for (int j = 0; j < 8; ++j) xa[j] = xn[(size_t)j * NPIX];
        }
        {
            short8v bf = *(const short8v*)&u.xs[0][h][wv * 32 + q31][0];
#pragma unroll
            for (int rb = 0; rb < 6; ++rb) {
                short8v af = *(const short8v*)&wqkv[(size_t)(rb * 32 + q31) * 256 + ks * 16 + h * 8];
                acc[rb] = __builtin_amdgcn_mfma_f32_32x32x16_bf16(af, bf, acc[rb], 0, 0, 0);
            }
        }
        {
            unsigned pk[4];
#pragma unroll
            for (int jj = 0; jj < 4; ++jj) pk[jj] = cvtpk(xbr[2*jj], xbr[2*jj+1]);
            *(uint4*)&u.xs[1][skb][sp][0] = *(uint4*)pk;
        }
        __syncthreads();

        if (ks < 14) {
            const float* xn = xb + (size_t)((ks + 3) * 16 + skb * 8) * NPIX;
#pragma unroll
            for (int j = 0; j < 8; ++j) xbr[j] = xn[(size_t)j * NPIX];
        }
        {
            short8v bf = *(const short8v*)&u.xs[1][h][wv * 32 + q31][0];
#pragma unroll
            for (int rb = 0; rb < 6; ++rb) {
                short8v af = *(const short8v*)&wqkv[(size_t)(rb * 32 + q31) * 256 + (ks + 1) * 16 + h * 8];
                acc[rb] = __builtin_amdgcn_mfma_f32_32x32x16_bf16(af, bf, acc[rb], 0, 0, 0);
            }
        }
        if (ks < 14) {
            unsigned pk[4];
#pragma unroll
            for (int jj = 0; jj < 4; ++jj) pk[jj] = cvtpk(xa[2*jj], xa[2*jj+1]);
            *(uint4*)&u.xs[0][skb][sp][0] = *(uint4*)pk;
        }
        __syncthreads();
    }

    // ---- Q epilogue (rb 0): full-res, bf16 [p][32]; pre-scaled by log2(e)
    {
        int pix = pixb + wv * 32 + q31;
        unsigned short* qout = &Qg[((size_t)b * NPIX + pix) * DQK];
#pragma unroll
        for (int m = 0; m < 4; ++m) {
            unsigned pk2[2];
            float v0 = (acc[0][m*4+0] + b_theta[4*h + 8*m + 0]) * LOG2E;
            float v1 = (acc[0][m*4+1] + b_theta[4*h + 8*m + 1]) * LOG2E;
            float v2 = (acc[0][m*4+2] + b_theta[4*h + 8*m + 2]) * LOG2E;
            float v3 = (acc[0][m*4+3] + b_theta[4*h + 8*m + 3]) * LOG2E;
            pk2[0] = cvtpk(v0, v1);
            pk2[1] = cvtpk(v2, v3);
            *(uint2*)&qout[8*m + 4*h] = *(uint2*)pk2;
        }
    }

    // ---- pooled epilogue (rb 1..5): horizontal max via shfl, halves to LDS
#pragma unroll
    for (int rb = 1; rb < 6; ++rb) {
#pragma unroll
        for (int r = 0; r < 16; ++r) {
            float v  = acc[rb][r];
            float o  = __shfl_xor(v, 1);
            float mx = fmaxf(v, o);
            if ((q31 & 1) == 0) {
                int row = (r & 3) + 8 * (r >> 2) + 4 * h;
                u.pool[wv >> 1][(rb - 1) * 32 + row][(wv & 1) * 16 + (q31 >> 1)] = mx;
            }
        }
    }
    __syncthreads();

    // ---- vertical max + bias + scatter to K/V frag layouts
    {
        int wx = t & 31;
        int pp = tile * 32 + wx;
#pragma unroll
        for (int i = 0; i < 20; ++i) {
            int ch = (t >> 5) * 20 + i;
            float v = fmaxf(u.pool[0][ch][wx], u.pool[1][ch][wx]);
            if (ch < 32) {
                v += b_phi[ch];
                Kg[(((size_t)b * 4 + (ch >> 3)) * NP4 + pp) * 8 + (ch & 7)] = f2bf(v);
            } else {
                int c = ch - 32;
                v += b_g[c];
                Vg[((size_t)b * 128 + (pp >> 3)) * (DV * 8) + (size_t)c * 8 + (pp & 7)] = f2bf(v);
            }
        }
    }
}

// ------- fused: flash attention + final conv + residual ---------------------
// Main loop: reg-resident K/V direct from global, no barriers, fixed-shift SM.
// Epilogue: software-pipelined cht loop — x prefetch 1-ahead, ls double-buffer,
// ONE barrier per cht; loads/stores stream continuously.
__global__ __launch_bounds__(256, 2) void flash_k(
    const unsigned short* __restrict__ Qg, const unsigned short* __restrict__ Kg,
    const unsigned short* __restrict__ Vg, const unsigned short* __restrict__ wab,
    const float* __restrict__ b_attn, const float* __restrict__ sigma,
    const float* __restrict__ x, float* __restrict__ out)
{
    __shared__ __align__(16) unsigned short os[4][16 * 33 * 8];  // 33.8 KB per-wave O^T
    __shared__ __align__(16) float ls[2][32][132];               // 33.8 KB dbuf bounce

    const int b    = blockIdx.y;
    const int t    = threadIdx.x;
    const int wv   = t >> 6;
    const int l    = t & 63;
    const int h    = l >> 5;
    const int q31  = l & 31;
    const int pxblk = blockIdx.x * QT;
    const int p0   = pxblk + wv * QW;

    const unsigned short* Kp = Kg + (size_t)b * 4 * NP4 * 8 + ((size_t)h * NP4 + q31) * 8;
    const unsigned short* Vp = Vg + (size_t)b * 128 * DV * 8 + h * 1024 + q31 * 8;

    short8v qf0 = ldg8(&Qg[((size_t)b * NPIX + p0 + q31) * DQK + h * 8]);
    short8v qf1 = ldg8(&Qg[((size_t)b * NPIX + p0 + q31) * DQK + 16 + h * 8]);

    f32x16 o0 = ZERO16, o1 = ZERO16, o2 = ZERO16, o3 = ZERO16;
    float lsum = 0.f;

    short8v kfA[4], kfB[4], vg[16];
#pragma unroll
    for (int i = 0; i < 4; ++i)
        kfA[i] = ldg8(Kp + (i >> 1) * (2 * NP4 * 8) + (i & 1) * 256);
#pragma unroll
    for (int g = 0; g < 4; ++g)
#pragma unroll
        for (int cc = 0; cc < 4; ++cc)
            vg[g * 4 + cc] = ldg8(Vp + g * 2048 + cc * 256);

    auto tile = [&](int kt, short8v (&kfc)[4], short8v (&kfn)[4], bool pref) {
        f32x16 s0 = ZERO16, s1 = ZERO16;
        s0 = __builtin_amdgcn_mfma_f32_32x32x16_bf16(kfc[0], qf0, s0, 0, 0, 0);
        s1 = __builtin_amdgcn_mfma_f32_32x32x16_bf16(kfc[1], qf0, s1, 0, 0, 0);
        s0 = __builtin_amdgcn_mfma_f32_32x32x16_bf16(kfc[2], qf1, s0, 0, 0, 0);
        s1 = __builtin_amdgcn_mfma_f32_32x32x16_bf16(kfc[3], qf1, s1, 0, 0, 0);

        if (pref) {
            const unsigned short* kp1 = Kp + (size_t)(kt + 1) * 512;
#pragma unroll
            for (int i = 0; i < 4; ++i)
                kfn[i] = ldg8(kp1 + (i >> 1) * (2 * NP4 * 8) + (i & 1) * 256);
        }

        float ts[16];
#pragma unroll
        for (int r = 0; r < 16; ++r) {
            s0[r] = exp2f(s0[r] - MFIX);
            s1[r] = exp2f(s1[r] - MFIX);
            ts[r] = s0[r] + s1[r];
        }
#pragma unroll
        for (int d = 8; d >= 1; d >>= 1)
#pragma unroll
            for (int r = 0; r < d; ++r) ts[r] += ts[r + d];
        lsum += ts[0] + __shfl_xor(ts[0], 32);

        unsigned ca[8], cb[8];
#pragma unroll
        for (int j = 0; j < 8; ++j) {
            ca[j] = cvtpk(s0[2*j], s0[2*j+1]);
            cb[j] = cvtpk(s1[2*j], s1[2*j+1]);
        }
        PLSWAP(ca[0], ca[2]); PLSWAP(ca[1], ca[3]);
        PLSWAP(ca[4], ca[6]); PLSWAP(ca[5], ca[7]);
        PLSWAP(cb[0], cb[2]); PLSWAP(cb[1], cb[3]);
        PLSWAP(cb[4], cb[6]); PLSWAP(cb[5], cb[7]);
        union { unsigned uu[4]; short8v v; } pa[4];
#pragma unroll
        for (int j = 0; j < 4; ++j) {
            pa[0].uu[j] = ca[j];     pa[1].uu[j] = ca[4 + j];
            pa[2].uu[j] = cb[j];     pa[3].uu[j] = cb[4 + j];
        }

        const unsigned short* vp1 = Vp + (size_t)(kt + 1) * 8192;
#pragma unroll
        for (int g = 0; g < 4; ++g) {
            o0 = __builtin_amdgcn_mfma_f32_32x32x16_bf16(pa[g].v, vg[g*4+0], o0, 0, 0, 0);
            o1 = __builtin_amdgcn_mfma_f32_32x32x16_bf16(pa[g].v, vg[g*4+1], o1, 0, 0, 0);
            o2 = __builtin_amdgcn_mfma_f32_32x32x16_bf16(pa[g].v, vg[g*4+2], o2, 0, 0, 0);
            o3 = __builtin_amdgcn_mfma_f32_32x32x16_bf16(pa[g].v, vg[g*4+3], o3, 0, 0, 0);
            if (pref) {
#pragma unroll
                for (int cc = 0; cc < 4; ++cc)
                    vg[g*4+cc] = ldg8(vp1 + g * 2048 + cc * 256);
            }
        }
    };

    for (int kt = 0; kt < 16; kt += 2) {
        tile(kt,     kfA, kfB, true);
        tile(kt + 1, kfB, kfA, kt + 1 < 15);
    }

    // ---- normalize + per-wave padded transpose (O^T as B-frag source)
    float rinv = 1.0f / lsum;
    unsigned short* osw = os[wv];
#pragma unroll
    for (int r = 0; r < 16; ++r) {
        int q = (r & 3) + 8 * (r >> 2) + 4 * h;
        float rn = __shfl(rinv, q);
        int e8 = l & 7;
        osw[(((q31 >> 3)     ) * 33 + q) * 8 + e8] = f2bf(o0[r] * rn);
        osw[(((q31 >> 3) +  4) * 33 + q) * 8 + e8] = f2bf(o1[r] * rn);
        osw[(((q31 >> 3) +  8) * 33 + q) * 8 + e8] = f2bf(o2[r] * rn);
        osw[(((q31 >> 3) + 12) * 33 + q) * 8 + e8] = f2bf(o3[r] * rn);
    }

    // ---- final conv + residual: pipelined stream (x prefetch + ls dbuf)
    const float sg  = sigma[0];
    const int  cl8  = t >> 5;                   // 0..7
    const int  px4  = (t & 31) * 4;             // 0..124

    float4 xv[2][4];
#pragma unroll
    for (int rep = 0; rep < 4; ++rep) {
        int ch = rep * 8 + cl8;
        xv[0][rep] = *(const float4*)&x[((size_t)b * 256 + ch) * NPIX + pxblk + px4];
    }

#pragma unroll
    for (int cht = 0; cht < 8; ++cht) {
        const int cur = cht & 1;
        if (cht < 7) {                          // prefetch next cht's residual
#pragma unroll
            for (int rep = 0; rep < 4; ++rep) {
                int ch = (cht + 1) * 32 + rep * 8 + cl8;
                xv[cur ^ 1][rep] =
                    *(const float4*)&x[((size_t)b * 256 + ch) * NPIX + pxblk + px4];
            }
        }

        f32x16 e = ZERO16;
#pragma unroll
        for (int ks16 = 0; ks16 < 8; ++ks16) {
            short8v wfv = ldg8(&wab[(size_t)(cht * 32 + q31) * DV + ks16 * 16 + h * 8]);
            short8v of  = *(const short8v*)&osw[((ks16 * 2 + h) * 33 + q31) * 8];
            e = __builtin_amdgcn_mfma_f32_32x32x16_bf16(wfv, of, e, 0, 0, 0);
        }
#pragma unroll
        for (int r = 0; r < 16; ++r) {
            int crow = (r & 3) + 8 * (r >> 2) + 4 * h;
            ls[cur][crow][wv * 32 + q31] = e[r];
        }
        __syncthreads();                        // ls[cur] complete block-wide
#pragma unroll
        for (int rep = 0; rep < 4; ++rep) {
            int cl = rep * 8 + cl8;
            int ch = cht * 32 + cl;
            float4 v = *(const float4*)&ls[cur][cl][px4];
            float bias = b_attn[ch];
            size_t idx = ((size_t)b * 256 + ch) * NPIX + pxblk + px4;
            float4 o;
            o.x = fmaf(sg, v.x + bias, xv[cur][rep].x);
            o.y = fmaf(sg, v.y + bias, xv[cur][rep].y);
            o.z = fmaf(sg, v.z + bias, xv[cur][rep].z);
            o.w = fmaf(sg, v.w + bias, xv[cur][rep].w);
            *(float4*)&out[idx] = o;
        }
        // no trailing barrier: next iter writes ls[cur^1]; ls[cur] is reused
        // only after the NEXT barrier, by which time these reads (consumed by
        // the stores above via lgkmcnt) are complete.
    }
}

extern "C" void kernel_launch(void* const* d_in, const int* in_sizes, int n_in,
                              void* d_out, int out_size, void* d_ws, size_t ws_size,
                              hipStream_t stream) {
    const float* x       = (const float*)d_in[0];
    const float* w_theta = (const float*)d_in[1];
    const float* b_theta = (const float*)d_in[2];
    const float* w_phi   = (const float*)d_in[3];
    const float* b_phi   = (const float*)d_in[4];
    const float* w_g     = (const float*)d_in[5];
    const float* b_g     = (const float*)d_in[6];
    const float* w_attn  = (const float*)d_in[7];
    const float* b_attn  = (const float*)d_in[8];
    const float* sigma   = (const float*)d_in[9];
    float* out = (float*)d_out;

    unsigned short* Qg   = (unsigned short*)d_ws;                 // 16*4096*32
    unsigned short* Kg   = Qg + (size_t)BATCH * NPIX * DQK;       // 16*4*1024*8
    unsigned short* Vg   = Kg + (size_t)BATCH * 4 * NP4 * 8;      // 16*128*128*8
    unsigned short* wab  = Vg + (size_t)BATCH * 128 * DV * 8;     // 256*128
    unsigned short* wqkv = wab + (size_t)256 * DV;                // 192*256

    wcvt_k    <<<dim3((192 * 256 + 256 * DV + 255) / 256), 256, 0, stream>>>(
        w_theta, w_phi, w_g, w_attn, wqkv, wab);
    conv_qkv_k<<<dim3(NPIX / 128, BATCH), 256, 0, stream>>>(
        x, wqkv, b_theta, b_phi, b_g, Qg, Kg, Vg);
    flash_k   <<<dim3(NPIX / QT, BATCH), 256, 0, stream>>>(
        Qg, Kg, Vg, wab, b_attn, sigma, x, out);
}